// Round 9
// baseline (288.348 us; speedup 1.0000x reference)
//
#include <hip/hip_runtime.h>
#include <hip/hip_bf16.h>
#include <stdint.h>

#define BATCH  8192
#define DIN    2048
#define DOUT   2048
#define NB     256
#define KSEL   26      // ceil(0.1*256)
#define GDELTA 1e-4f   // top-k boundary refine threshold

typedef __attribute__((ext_vector_type(4))) float f32x4;
typedef __attribute__((ext_vector_type(8))) __bf16 bf16x8;
typedef __attribute__((ext_vector_type(8))) unsigned short u16x8;

__device__ __forceinline__ float bf2f(unsigned short u){
  union { unsigned int i; float f; } v; v.i = ((unsigned int)u) << 16; return v.f;
}
__device__ __forceinline__ unsigned short f2bf_c(float f){
  __bf16 b = (__bf16)f;
  union { __bf16 b; unsigned short u; } v; v.b = b; return v.u;
}
// async global->LDS, 16B per lane; LDS dest must be wave-uniform base.
__device__ __forceinline__ void gload16(const unsigned short* g, unsigned short* l){
  __builtin_amdgcn_global_load_lds(
      (const __attribute__((address_space(1))) void*)g,
      (__attribute__((address_space(3))) void*)l, 16, 0, 0);
}

// Tile image layout (T21): element (row, k) of a [R][64] bf16 tile lives at
// u16 offset row*64 + ((chunk ^ (row&7))<<3) + (k&7), chunk = (k&63)>>3.
// Global tiled tensors store these images contiguously so global_load_lds
// with a LINEAR dest reproduces the swizzled LDS image byte-for-byte.

// ---------------- K0b: W -> tiled-swizzled bf16 (16 q x 32 kstep x 16KB) ----
__global__ __launch_bounds__(256) void conv_wt2(const float* __restrict__ w,
                                                unsigned short* __restrict__ wtt)
{
  __shared__ float tl[64][65];
  const int k0 = blockIdx.x * 64;
  const int n0 = blockIdx.y * 64;
  const int c  = threadIdx.x & 63;
  const int r4 = threadIdx.x >> 6;
  #pragma unroll
  for (int i = 0; i < 16; i++){
    const int r = r4 * 16 + i;
    tl[r][c] = w[(size_t)(k0 + r) * DOUT + n0 + c];
  }
  __syncthreads();
  const int n  = threadIdx.x & 63;
  const int cp = threadIdx.x >> 6;
  const int gn = n0 + n;
  const size_t base = ((size_t)(gn >> 7) * 32 + (k0 >> 6)) * 8192 + (size_t)(gn & 127) * 64;
  const int sw = gn & 7;
  #pragma unroll
  for (int u = 0; u < 2; u++){
    const int cc = cp * 2 + u;
    u16x8 o;
    #pragma unroll
    for (int j = 0; j < 8; j++) o[j] = f2bf_c(tl[cc * 8 + j][n]);
    *(u16x8*)&wtt[base + ((cc ^ sw) << 3)] = o;
  }
}

// ---------------- K0c: gw -> tiled-swizzled hi/lo (4 ct x 32 ks x 8KB) ------
__global__ __launch_bounds__(256) void conv_gwt2(const float* __restrict__ gw,
    unsigned short* __restrict__ ght, unsigned short* __restrict__ glt)
{
  __shared__ float tl[64][65];
  const int k0 = blockIdx.x * 64;
  const int c0 = blockIdx.y * 64;
  const int c  = threadIdx.x & 63;
  const int r4 = threadIdx.x >> 6;
  #pragma unroll
  for (int i = 0; i < 16; i++){
    const int r = r4 * 16 + i;
    tl[r][c] = gw[(size_t)(k0 + r) * NB + c0 + c];
  }
  __syncthreads();
  const int n  = threadIdx.x & 63;
  const int cp = threadIdx.x >> 6;
  const size_t base = ((size_t)(c0 >> 6) * 32 + (k0 >> 6)) * 4096 + (size_t)n * 64;
  const int sw = n & 7;
  #pragma unroll
  for (int u = 0; u < 2; u++){
    const int cc = cp * 2 + u;
    u16x8 hi, lo;
    #pragma unroll
    for (int j = 0; j < 8; j++){
      const float v = tl[cc * 8 + j][n];
      const __bf16 hb = (__bf16)v;
      union { __bf16 b; unsigned short u; } uh; uh.b = hb;
      hi[j] = uh.u;
      lo[j] = f2bf_c(v - (float)hb);
    }
    const int off = (cc ^ sw) << 3;
    *(u16x8*)&ght[base + off] = hi;
    *(u16x8*)&glt[base + off] = lo;
  }
}

// ---------------- K1: gate GEMM, 3-term hi/lo bf16 MFMA ---------------------
// Block 128b x 64c, 4 waves (wave 64b x 32c), BK=64, K-split 2.
// B (g hi/lo): global_load_lds double-buffered from pre-swizzled tiles.
// A (x): f32 -> hi/lo cvt in regs -> swizzled ds_write (T14 x-prefetch);
// c-tile 0 blocks also emit xb in the tiled layout (same bytes as Axh).
__global__ __launch_bounds__(256) void gate_v3(
    const float* __restrict__ x,
    const unsigned short* __restrict__ ght,
    const unsigned short* __restrict__ glt,
    float* __restrict__ part,
    unsigned short* __restrict__ xbt)
{
  __shared__ unsigned short Axh[128 * 64], Axl[128 * 64];   // 32 KB
  __shared__ unsigned short Bh[2][64 * 64], Bl[2][64 * 64]; // 32 KB

  const int b0   = blockIdx.x * 128;
  const int ct   = blockIdx.y;          // c-tile 0..3
  const int z    = blockIdx.z;          // K-split 0/1
  const int ks0  = z * 16;              // k-step base
  const int t    = threadIdx.x;
  const int lane = t & 63;
  const int wid  = t >> 6;
  const int bw   = wid & 1;             // b-half: rows bw*64
  const int cw   = wid >> 1;            // c-half: cols cw*32
  const int l15  = lane & 15;
  const int l4   = lane >> 4;
  const bool emit = (blockIdx.y == 0);

  const int ar  = t >> 1;               // A-stage row 0..127
  const int ah4 = (t & 1) * 4;          // A-stage chunk base 0/4

  f32x4 acc[4][2];
  #pragma unroll
  for (int m = 0; m < 4; m++)
    #pragma unroll
    for (int n = 0; n < 2; n++) acc[m][n] = (f32x4)0.0f;

  int aoff[2][4], boff[2][2];
  #pragma unroll
  for (int ksi = 0; ksi < 2; ksi++){
    const int chunk = ksi * 4 + l4;
    #pragma unroll
    for (int m = 0; m < 4; m++){
      const int row = bw * 64 + m * 16 + l15;
      aoff[ksi][m] = row * 64 + ((chunk ^ (row & 7)) << 3);
    }
    #pragma unroll
    for (int n = 0; n < 2; n++){
      const int row = cw * 32 + n * 16 + l15;
      boff[ksi][n] = row * 64 + ((chunk ^ (row & 7)) << 3);
    }
  }

  f32x4 xr[8];
  auto LOADX = [&](int s){
    const float* xp = &x[(size_t)(b0 + ar) * DIN + (size_t)(ks0 + s) * 64 + ah4 * 8];
    #pragma unroll
    for (int j = 0; j < 8; j++) xr[j] = ((const f32x4*)xp)[j];
  };
  auto GLOADB = [&](int bb, int s){
    const size_t base = ((size_t)ct * 32 + (ks0 + s)) * 4096;
    #pragma unroll
    for (int i = 0; i < 2; i++){
      const int slot = (wid * 2 + i) * 512;
      gload16(ght + base + slot + lane * 8, &Bh[bb][slot]);
      gload16(glt + base + slot + lane * 8, &Bl[bb][slot]);
    }
  };
  auto WRITEA = [&](int s){
    const int sw = ar & 7;
    const size_t gb = ((size_t)(b0 >> 7) * 32 + (ks0 + s)) * 8192 + (size_t)ar * 64;
    #pragma unroll
    for (int j = 0; j < 4; j++){
      u16x8 hi, lo;
      #pragma unroll
      for (int e = 0; e < 8; e++){
        const float v = xr[j * 2 + (e >> 2)][e & 3];
        const __bf16 hb = (__bf16)v;
        union { __bf16 b; unsigned short u; } uh; uh.b = hb;
        hi[e] = uh.u;
        lo[e] = f2bf_c(v - (float)hb);
      }
      const int c8 = ((ah4 + j) ^ sw) << 3;
      *(u16x8*)&Axh[ar * 64 + c8] = hi;
      *(u16x8*)&Axl[ar * 64 + c8] = lo;
      if (emit) *(u16x8*)&xbt[gb + c8] = hi;
    }
  };

  GLOADB(0, 0);
  LOADX(0);
  int buf = 0;
  #pragma unroll 1
  for (int s = 0; s < 16; s++){
    __syncthreads();                    // prev compute done; B[buf] DMA + xr drained
    WRITEA(s);
    __syncthreads();                    // A visible
    if (s < 15){ GLOADB(buf ^ 1, s + 1); LOADX(s + 1); }  // overlap compute
    #pragma unroll
    for (int ksi = 0; ksi < 2; ksi++){
      bf16x8 ah[4], al[4], bh[2], bl[2];
      #pragma unroll
      for (int m = 0; m < 4; m++){
        ah[m] = *(const bf16x8*)&Axh[aoff[ksi][m]];
        al[m] = *(const bf16x8*)&Axl[aoff[ksi][m]];
      }
      #pragma unroll
      for (int n = 0; n < 2; n++){
        bh[n] = *(const bf16x8*)&Bh[buf][boff[ksi][n]];
        bl[n] = *(const bf16x8*)&Bl[buf][boff[ksi][n]];
      }
      #pragma unroll
      for (int m = 0; m < 4; m++)
        #pragma unroll
        for (int n = 0; n < 2; n++){
          acc[m][n] = __builtin_amdgcn_mfma_f32_16x16x32_bf16(ah[m], bh[n], acc[m][n], 0, 0, 0);
          acc[m][n] = __builtin_amdgcn_mfma_f32_16x16x32_bf16(al[m], bh[n], acc[m][n], 0, 0, 0);
          acc[m][n] = __builtin_amdgcn_mfma_f32_16x16x32_bf16(ah[m], bl[n], acc[m][n], 0, 0, 0);
        }
    }
    buf ^= 1;
  }

  float* dst = part + (size_t)z * BATCH * NB;
  #pragma unroll
  for (int m = 0; m < 4; m++){
    const int brow = b0 + bw * 64 + m * 16 + l4 * 4;
    #pragma unroll
    for (int n = 0; n < 2; n++){
      const int ccol = ct * 64 + cw * 32 + n * 16 + l15;
      #pragma unroll
      for (int r = 0; r < 4; r++)
        dst[(size_t)(brow + r) * NB + ccol] = acc[m][n][r];
    }
  }
}

// ---------------- K2: sum 2 partials, top-26 + renorm + boundary flag -------
__global__ __launch_bounds__(256) void topk(float* __restrict__ part,
    const float* __restrict__ gb, int* __restrict__ flags)
{
  const int lane = threadIdx.x & 63;
  const int row  = blockIdx.x * 4 + (threadIdx.x >> 6);
  f32x4* p0 = (f32x4*)&part[(size_t)row * NB];
  const f32x4* p1 = (const f32x4*)&part[(size_t)(BATCH + row) * NB];
  const f32x4* gbv = (const f32x4*)gb;
  f32x4 v = p0[lane] + p1[lane] + gbv[lane];

  const float NEG = -3.402823466e38f;
  float w0 = v[0], w1 = v[1], w2 = v[2], w3 = v[3];
  float thr = 0.f, nxt = 0.f;
  for (int it = 0; it < KSEL + 1; it++){
    float lm = fmaxf(fmaxf(w0, w1), fmaxf(w2, w3));
    float wm = lm;
    #pragma unroll
    for (int off = 32; off; off >>= 1) wm = fmaxf(wm, __shfl_xor(wm, off, 64));
    unsigned long long ball = __ballot(lm == wm);
    int first = __ffsll(ball) - 1;
    if (lane == first){
      if      (w0 == wm) w0 = NEG;
      else if (w1 == wm) w1 = NEG;
      else if (w2 == wm) w2 = NEG;
      else               w3 = NEG;
    }
    if (it < KSEL) thr = wm; else nxt = wm;
  }
  if (lane == 0) flags[row] = (thr - nxt < GDELTA) ? 1 : 0;

  float s = 0.f;
  #pragma unroll
  for (int j = 0; j < 4; j++) s += (v[j] >= thr) ? v[j] : 0.f;
  #pragma unroll
  for (int off = 32; off; off >>= 1) s += __shfl_xor(s, off, 64);
  const float d = s * (1.0f / NB);
  f32x4 o;
  #pragma unroll
  for (int j = 0; j < 4; j++) o[j] = (v[j] >= thr) ? v[j] / d : 0.f;
  p0[lane] = o;
}

// ---------------- K2b: exact recompute of boundary-ambiguous rows -----------
__global__ __launch_bounds__(256) void refine(
    const float* __restrict__ x, const float* __restrict__ gw,
    const float* __restrict__ gb, const int* __restrict__ flags,
    float* __restrict__ part)
{
  const int lane = threadIdx.x & 63;
  const int row  = blockIdx.x * 4 + (threadIdx.x >> 6);
  if (!flags[row]) return;

  f32x4 acc0 = (f32x4)0.f, acc1 = (f32x4)0.f;
  const float* xp = &x[(size_t)row * DIN];
  #pragma unroll 8
  for (int k = 0; k < 1024; k++){
    const float xv = xp[k];
    const f32x4 wv = *(const f32x4*)&gw[(size_t)k * NB + lane * 4];
    #pragma unroll
    for (int j = 0; j < 4; j++) acc0[j] = fmaf(xv, wv[j], acc0[j]);
  }
  #pragma unroll 8
  for (int k = 1024; k < 2048; k++){
    const float xv = xp[k];
    const f32x4 wv = *(const f32x4*)&gw[(size_t)k * NB + lane * 4];
    #pragma unroll
    for (int j = 0; j < 4; j++) acc1[j] = fmaf(xv, wv[j], acc1[j]);
  }
  const f32x4 gbv = *(const f32x4*)&gb[lane * 4];
  f32x4 v;
  #pragma unroll
  for (int j = 0; j < 4; j++) v[j] = acc0[j] + acc1[j] + gbv[j];

  const float NEG = -3.402823466e38f;
  float w0 = v[0], w1 = v[1], w2 = v[2], w3 = v[3];
  float thr = 0.f;
  for (int it = 0; it < KSEL; it++){
    float lm = fmaxf(fmaxf(w0, w1), fmaxf(w2, w3));
    float wm = lm;
    #pragma unroll
    for (int off = 32; off; off >>= 1) wm = fmaxf(wm, __shfl_xor(wm, off, 64));
    unsigned long long ball = __ballot(lm == wm);
    int first = __ffsll(ball) - 1;
    if (lane == first){
      if      (w0 == wm) w0 = NEG;
      else if (w1 == wm) w1 = NEG;
      else if (w2 == wm) w2 = NEG;
      else               w3 = NEG;
    }
    thr = wm;
  }
  float s = 0.f;
  #pragma unroll
  for (int j = 0; j < 4; j++) s += (v[j] >= thr) ? v[j] : 0.f;
  #pragma unroll
  for (int off = 32; off; off >>= 1) s += __shfl_xor(s, off, 64);
  const float d = s * (1.0f / NB);
  f32x4 o;
  #pragma unroll
  for (int j = 0; j < 4; j++) o[j] = (v[j] >= thr) ? v[j] / d : 0.f;
  *(f32x4*)&part[(size_t)row * NB + lane * 4] = o;
}

// ---------------- K3: main GEMM, m97 template + accumulator-level gating ----
// 128b x 128n tile (one q), 4 waves 64x64, BK=64, double-buffered LDS fed by
// global_load_lds from pre-swizzled tiles (zero staging VALU / ds_writes).
// Gating: accP accumulates one p-slice (128 k = 2 steps); fold accT += g*accP.
__global__ __launch_bounds__(256) void main_v3(
    const unsigned short* __restrict__ xbt,
    const unsigned short* __restrict__ wtt,
    const float* __restrict__ g,
    const float* __restrict__ bias,
    float* __restrict__ out)
{
  __shared__ unsigned short XA[2][128 * 64], WB[2][128 * 64];  // 64 KB
  __shared__ float gl[128 * 17];

  const int f  = blockIdx.x;
  const int q  = f >> 6;
  const int bt = (f & 7) * 8 + ((f >> 3) & 7);   // XCD-aware: q-mates co-XCD
  const int b0 = bt * 128;
  const int t    = threadIdx.x;
  const int lane = t & 63;
  const int wid  = t >> 6;
  const int wr   = (wid >> 1) * 64;
  const int wc   = (wid & 1) * 64;
  const int l15  = lane & 15;
  const int l4   = lane >> 4;

  for (int e = t; e < 128 * 16; e += 256){
    const int r = e >> 4, p = e & 15;
    gl[r * 17 + p] = g[(size_t)(b0 + r) * NB + p * 16 + q];
  }

  f32x4 accT[4][4], accP[4][4];
  #pragma unroll
  for (int m = 0; m < 4; m++)
    #pragma unroll
    for (int n = 0; n < 4; n++){ accT[m][n] = (f32x4)0.0f; accP[m][n] = (f32x4)0.0f; }

  int aoff[2][4], boff[2][4];
  #pragma unroll
  for (int ksi = 0; ksi < 2; ksi++){
    const int chunk = ksi * 4 + l4;
    #pragma unroll
    for (int m = 0; m < 4; m++){
      const int row = wr + m * 16 + l15;
      aoff[ksi][m] = row * 64 + ((chunk ^ (row & 7)) << 3);
    }
    #pragma unroll
    for (int n = 0; n < 4; n++){
      const int row = wc + n * 16 + l15;
      boff[ksi][n] = row * 64 + ((chunk ^ (row & 7)) << 3);
    }
  }

  const unsigned short* asrc0 = xbt + (size_t)bt * 32 * 8192;
  const unsigned short* bsrc0 = wtt + (size_t)q  * 32 * 8192;

  auto GLOAD = [&](int bb, int kp){
    const unsigned short* as = asrc0 + (size_t)kp * 8192;
    const unsigned short* bs = bsrc0 + (size_t)kp * 8192;
    #pragma unroll
    for (int i = 0; i < 4; i++){
      const int slot = (wid * 4 + i) * 512;
      gload16(as + slot + lane * 8, &XA[bb][slot]);
      gload16(bs + slot + lane * 8, &WB[bb][slot]);
    }
  };

  GLOAD(0, 0);
  int buf = 0;
  #pragma unroll 1
  for (int kp = 0; kp < 32; kp++){
    __syncthreads();                    // DMA(cur) drained; prev compute done
    if (kp < 31) GLOAD(buf ^ 1, kp + 1);
    #pragma unroll
    for (int ksi = 0; ksi < 2; ksi++){
      bf16x8 a[4], b[4];
      #pragma unroll
      for (int m = 0; m < 4; m++) a[m] = *(const bf16x8*)&XA[buf][aoff[ksi][m]];
      #pragma unroll
      for (int n = 0; n < 4; n++) b[n] = *(const bf16x8*)&WB[buf][boff[ksi][n]];
      #pragma unroll
      for (int m = 0; m < 4; m++)
        #pragma unroll
        for (int n = 0; n < 4; n++)
          accP[m][n] = __builtin_amdgcn_mfma_f32_16x16x32_bf16(a[m], b[n], accP[m][n], 0, 0, 0);
    }
    if (kp & 1){                        // p-slice complete: fold with gates
      const int p = kp >> 1;
      #pragma unroll
      for (int m = 0; m < 4; m++){
        const int rb = wr + m * 16 + l4 * 4;
        f32x4 g4;
        #pragma unroll
        for (int r = 0; r < 4; r++) g4[r] = gl[(rb + r) * 17 + p];
        #pragma unroll
        for (int n = 0; n < 4; n++){
          accT[m][n] += g4 * accP[m][n];
          accP[m][n] = (f32x4)0.0f;
        }
      }
    }
    buf ^= 1;
  }

  #pragma unroll
  for (int n = 0; n < 4; n++){
    const int col = q * 128 + wc + n * 16 + l15;
    const float bv = bias[col];
    #pragma unroll
    for (int m = 0; m < 4; m++){
      #pragma unroll
      for (int r = 0; r < 4; r++){
        const int row = b0 + wr + m * 16 + l4 * 4 + r;
        out[(size_t)row * DOUT + col] = accT[m][n][r] + bv;
      }
    }
  }
}

// ---------------- launch -----------------------------------------------------
extern "C" void kernel_launch(void* const* d_in, const int* in_sizes, int n_in,
                              void* d_out, int out_size, void* d_ws, size_t ws_size,
                              hipStream_t stream)
{
  const float* x    = (const float*)d_in[0];
  const float* w    = (const float*)d_in[1];
  const float* bias = (const float*)d_in[2];
  const float* gw   = (const float*)d_in[3];
  const float* gb   = (const float*)d_in[4];
  float* out = (float*)d_out;

  // ws (<=50.1 MiB):
  //   [0,8M)   part split 0 (becomes final gates)
  //   [8,16M)  part split 1 (dead after topk) -> overlaid by wtt (8 MiB, tiled W^T)
  //   [16,48M) xbt: tiled-swizzled bf16(x), emitted by gate_v3
  //   [48,49M) ght tiled | [49,50M) glt tiled | [50M,..) flags
  char* wsb = (char*)d_ws;
  float*          part = (float*)wsb;
  unsigned short* wtt  = (unsigned short*)(wsb + (size_t)8  * 1024 * 1024);
  unsigned short* xbt  = (unsigned short*)(wsb + (size_t)16 * 1024 * 1024);
  unsigned short* ght  = (unsigned short*)(wsb + (size_t)48 * 1024 * 1024);
  unsigned short* glt  = (unsigned short*)(wsb + (size_t)49 * 1024 * 1024);
  int*            flg  = (int*)           (wsb + (size_t)50 * 1024 * 1024);

  conv_gwt2<<<dim3(DIN / 64, NB / 64), 256, 0, stream>>>(gw, ght, glt);
  gate_v3  <<<dim3(BATCH / 128, 4, 2), 256, 0, stream>>>(x, ght, glt, part, xbt);
  topk     <<<BATCH / 4, 256, 0, stream>>>(part, gb, flg);
  refine   <<<BATCH / 4, 256, 0, stream>>>(x, gw, gb, flg, part);
  conv_wt2 <<<dim3(DIN / 64, DOUT / 64), 256, 0, stream>>>(w, wtt);
  main_v3  <<<1024, 256, 0, stream>>>(xbt, wtt, part, bias, out);
}